// Round 13
// baseline (226.665 us; speedup 1.0000x reference)
//
#include <hip/hip_runtime.h>

// GCN: 2x GCNConv(128->128) + relu, then Linear(128->40).
// R22: degree-sorted gather order (attacks wave divergence, the newly
//  identified fixed per-row cost: each wave64 = 4 groups with independent
//  Poisson(16) degrees, loop runs to max4(lenp)=23.5 vs mean 19.2; block
//  barrier waits max16=26.3). bin_to_csr now emits perm[]: its 512 nodes
//  counting-sorted by lenp bucket (block-local, 8 buckets). Gathers process
//  perm order -> uniform lenp per wave AND per block. Arithmetic per node
//  unchanged -> absmax must be exactly 1.342773e-3. Invalid tail slots map
//  to node 0 (duplicate recompute, identical bytes -> benign).
//  Unchanged from R21: fused setup; layer-1 single-term bf16 GEMM -> fp8 ht;
//  out = A_norm (g1 @ (W2 Wout)) + (b2 Wout + bout); z 40 feats fp16 @
//  stride 64 (1 line/row, cols 48-63 unused); 256-bucket two-phase CSR
//  build (rows padded >=8, x8, zero-row index n); gathers 16 lanes/row,
//  8-deep pipelines, independent loads hoisted.

typedef __attribute__((ext_vector_type(8))) short short8;
typedef __attribute__((ext_vector_type(4))) float floatx4;
typedef __attribute__((ext_vector_type(2))) float floatx2;
typedef _Float16 f16;
typedef __attribute__((ext_vector_type(4))) _Float16 half4;

#define CSR_STRIDE 64    // max in-degree ~40 for E=1.6M,N=100k
#define CH 4096          // edges per phase-A block (391 blocks)
#define BCAP2 10240      // per-bucket capacity (mean 8192, +22 sigma)

static __device__ inline unsigned short f32_to_bf16(float f) {
    unsigned u = __float_as_uint(f);
    unsigned r = (u + 0x7FFFu + ((u >> 16) & 1u)) >> 16;   // round-nearest-even
    return (unsigned short)r;
}
static __device__ inline float bf16_to_f32(unsigned short h) {
    return __uint_as_float(((unsigned)h) << 16);
}
static __device__ inline void split2(float v, unsigned short& h, unsigned short& l) {
    h = f32_to_bf16(v);
    l = f32_to_bf16(v - bf16_to_f32(h));
}
// accumulate 8 fp8(e4m3) bytes (packed in uint2) into s2[0..3] (float2 lanes)
static __device__ __forceinline__ void fp8x8_acc(floatx2* s2, uint2 v) {
    s2[0] += __builtin_amdgcn_cvt_pk_f32_fp8(v.x, false);
    s2[1] += __builtin_amdgcn_cvt_pk_f32_fp8(v.x, true);
    s2[2] += __builtin_amdgcn_cvt_pk_f32_fp8(v.y, false);
    s2[3] += __builtin_amdgcn_cvt_pk_f32_fp8(v.y, true);
}

// ---------- setup1: Wc/bc build + W1 split + bcur clear + zero rows ----------

__global__ __launch_bounds__(256) void setup1(const float* __restrict__ W2,
                                              const float* __restrict__ Wout,
                                              const float* __restrict__ b2,
                                              const float* __restrict__ bout,
                                              const float* __restrict__ W1,
                                              float* __restrict__ Wc,
                                              float* __restrict__ bc,
                                              unsigned short* __restrict__ wf1,
                                              int* __restrict__ bcur,
                                              unsigned* __restrict__ htz,
                                              unsigned* __restrict__ zz) {
    int tid = blockIdx.x * 256 + threadIdx.x;
    if (tid < 5120) {
        int i = tid / 40, j = tid - (tid / 40) * 40;
        float s = 0.f;
        for (int k = 0; k < 128; k++) s = fmaf(W2[i * 128 + k], Wout[k * 40 + j], s);
        Wc[i * 40 + j] = s;
    } else if (tid < 5160) {
        int j = tid - 5120;
        float s = bout[j];
        for (int k = 0; k < 128; k++) s = fmaf(b2[k], Wout[k * 40 + j], s);
        bc[j] = s;
    } else if (tid < 21544) {                  // W1 bf16 split (hi only)
        int e = tid - 5160;
        int k = e >> 7, nn = e & 127;
        int c = nn >> 4, s = k >> 5;
        int lane = (nn & 15) | (((k >> 3) & 3) << 4);
        int j = k & 7;
        int o = ((c * 4 + s) * 64 + lane) * 8 + j;
        wf1[o] = f32_to_bf16(W1[e]);
    } else if (tid < 25640) {                  // bcur clear (256*16 ints)
        bcur[tid - 21544] = 0;
    } else if (tid < 25672) {                  // ht zero row (128 B)
        htz[tid - 25640] = 0u;
    } else if (tid < 25704) {                  // z zero row (128 B)
        zz[tid - 25672] = 0u;
    }
}

// ---------- setup2: Wc -> frag-major bf16 hi/lo (needs Wcf from setup1) ----------

__global__ __launch_bounds__(256) void setup2(const float* __restrict__ Wcf,
                                              unsigned short* __restrict__ wfc) {
    int id = blockIdx.x * 256 + threadIdx.x;
    if (id < 6144) {                           // Wc 128x48 (cols 40..47 zero)
        int j = id & 7, lane = (id >> 3) & 63, cs = id >> 9;
        int c = cs >> 2, s = cs & 3;
        int k = s * 32 + ((lane >> 4) & 3) * 8 + j;
        int nn = c * 16 + (lane & 15);
        float v = (nn < 40) ? Wcf[k * 40 + nn] : 0.f;
        unsigned short h, l;
        split2(v, h, l);
        wfc[id] = h;
        wfc[6144 + id] = l;
    }
}

// ---------- CSR phase A: block-local binning into 256 buckets (dst>>9) ----------

__global__ __launch_bounds__(256) void bin_scatter(const int* __restrict__ src,
                                                   const int* __restrict__ dst,
                                                   int* __restrict__ bcur,
                                                   unsigned* __restrict__ bstore, int e) {
    __shared__ int hist[256];
    __shared__ int gbase[256];
    __shared__ int curs[256];
    int t = threadIdx.x;
    hist[t] = 0;
    __syncthreads();
    int tot4 = e >> 2;                       // e % 4 == 0
    int base4 = blockIdx.x * (CH / 4);
    unsigned pay[16];
    int cbv[16];
    bool vg[4];
    #pragma unroll
    for (int j = 0; j < 4; j++) {
        int i4 = base4 + t + 256 * j;
        vg[j] = (i4 < tot4);
        if (vg[j]) {
            int4 s4 = ((const int4*)src)[i4];
            int4 d4 = ((const int4*)dst)[i4];
            int dd[4] = {d4.x, d4.y, d4.z, d4.w};
            int ss[4] = {s4.x, s4.y, s4.z, s4.w};
            #pragma unroll
            for (int q = 0; q < 4; q++) {
                int cb = dd[q] >> 9;
                cbv[j * 4 + q] = cb;
                pay[j * 4 + q] = (unsigned)ss[q] | ((unsigned)(dd[q] & 511) << 17);
                atomicAdd(&hist[cb], 1);
            }
        }
    }
    __syncthreads();
    gbase[t] = atomicAdd(&bcur[t * 16], hist[t]);   // 256 returning atomics/block
    curs[t] = 0;
    __syncthreads();
    #pragma unroll
    for (int j = 0; j < 4; j++) {
        if (vg[j]) {
            #pragma unroll
            for (int q = 0; q < 4; q++) {
                int b = cbv[j * 4 + q];
                int pos = atomicAdd(&curs[b], 1);       // LDS returning atomic
                int o = gbase[b] + pos;
                if (o < BCAP2) bstore[(size_t)b * BCAP2 + o] = pay[j * 4 + q];
            }
        }
    }
}

// ---------- CSR phase B: bucket -> CSR rows; cnt/dinv; degree-sorted perm ----------
// Pads each row to a multiple of 8 AND at least 8 entries with index n (zero
// operand row). Then counting-sorts the block's 512 nodes by lenp bucket into
// perm[b*512 ...] so gather blocks get uniform-degree dst groups. Invalid
// tail slots (node >= n) map to node 0 (benign duplicate recompute).

__global__ __launch_bounds__(1024) void bin_to_csr(const int* __restrict__ bcur,
                                                   const unsigned* __restrict__ bstore,
                                                   int* __restrict__ csr,
                                                   int* __restrict__ cnt,
                                                   float* __restrict__ dinv,
                                                   int* __restrict__ perm, int n) {
    __shared__ int lcur[512];
    __shared__ int bhist[8];
    __shared__ int bbase[8];
    int b = blockIdx.x;
    int t = threadIdx.x;
    if (t < 512) lcur[t] = 0;
    if (t >= 512 && t < 520) bhist[t - 512] = 0;
    __syncthreads();
    int cb = bcur[b * 16];
    if (cb > BCAP2) cb = BCAP2;
    const unsigned* bs = bstore + (size_t)b * BCAP2;
    for (int i = t; i < cb; i += 1024) {
        unsigned v = bs[i];
        int dl = v >> 17;                    // 9-bit local dst
        int pos = atomicAdd(&lcur[dl], 1);
        if (pos < CSR_STRIDE) {
            int node = (b << 9) | dl;
            csr[(size_t)node * CSR_STRIDE + pos] = (int)(v & 0x1FFFFu);
        }
    }
    __syncthreads();
    int node = 0, mybkt = 0, mypos = 0;
    if (t < 512) {
        node = (b << 9) + t;
        int c = 0;
        if (node < n) {
            c = min(lcur[t], CSR_STRIDE);
            cnt[node] = c;
            dinv[node] = rsqrtf((float)c + 1.0f);   // +1 self-loop
            int end = (c + 7) & ~7;
            if (end < 8) end = 8;                   // entries 0..7 always valid
            size_t base = (size_t)node * CSR_STRIDE;
            for (int k = c; k < end; k++) csr[base + k] = n;   // zero row
        }
        int lenp8 = (c + 7) >> 3;
        if (lenp8 < 1) lenp8 = 1;                   // lenp/8 in 1..8
        mybkt = lenp8 - 1;
        mypos = atomicAdd(&bhist[mybkt], 1);
    }
    __syncthreads();
    if (t == 0) {
        int s = 0;
        #pragma unroll
        for (int i = 0; i < 8; i++) { bbase[i] = s; s += bhist[i]; }
    }
    __syncthreads();
    if (t < 512) {
        perm[(b << 9) + bbase[mybkt] + mypos] = (node < n) ? node : 0;
    }
}

// ---------- layer-1 GEMM (LDS-staged, single bf16 term): ht = fp8((x@W1)*dinv) ----------

__global__ __launch_bounds__(256, 2) void gemm_mfma(const float* __restrict__ A,
                                                    const unsigned short* __restrict__ Wf,
                                                    const float* __restrict__ dinv,
                                                    unsigned char* __restrict__ ht, int M) {
    __shared__ __align__(16) unsigned short Wl[16384];   // hi only
    {
        const float4* wsrc = (const float4*)Wf;
        float4* wdst = (float4*)Wl;
        #pragma unroll
        for (int i = 0; i < 8; i++) wdst[threadIdx.x + 256 * i] = wsrc[threadIdx.x + 256 * i];
    }
    int wave = threadIdx.x >> 6, lane = threadIdx.x & 63;
    int mlo = lane & 15, kq = lane >> 4;
    int row_base = blockIdx.x * 128 + wave * 32;

    short8 a[2][4];
    #pragma unroll
    for (int rt = 0; rt < 2; rt++) {
        int row = row_base + rt * 16 + mlo;
        if (row > M - 1) row = M - 1;
        const float* pa = A + (size_t)row * 128 + kq * 8;
        #pragma unroll
        for (int s = 0; s < 4; s++) {
            float u[8];
            *(float4*)&u[0] = *(const float4*)(pa + s * 32);
            *(float4*)&u[4] = *(const float4*)(pa + s * 32 + 4);
            short8 ah;
            #pragma unroll
            for (int j = 0; j < 8; j++) ah[j] = (short)f32_to_bf16(u[j]);
            a[rt][s] = ah;
        }
    }
    floatx4 acc[2][8];
    #pragma unroll
    for (int rt = 0; rt < 2; rt++)
        #pragma unroll
        for (int c = 0; c < 8; c++) acc[rt][c] = (floatx4){0.f, 0.f, 0.f, 0.f};
    __syncthreads();

    #pragma unroll
    for (int c = 0; c < 8; c++) {
        #pragma unroll
        for (int s = 0; s < 4; s++) {
            int fo = ((c * 4 + s) * 64 + lane) * 8;
            short8 bhi = *(const short8*)&Wl[fo];
            #pragma unroll
            for (int rt = 0; rt < 2; rt++)
                acc[rt][c] = __builtin_amdgcn_mfma_f32_16x16x32_bf16(a[rt][s], bhi, acc[rt][c], 0, 0, 0);
        }
    }
    #pragma unroll
    for (int rt = 0; rt < 2; rt++) {
        int r0 = row_base + rt * 16 + kq * 4;
        #pragma unroll
        for (int r = 0; r < 4; r++) {
            int row = r0 + r;
            if (row >= M) continue;
            float dd = dinv[row];
            unsigned char* hp = ht + (size_t)row * 128 + mlo;
            #pragma unroll
            for (int c = 0; c < 8; c++) {
                float v = acc[rt][c][r] * dd;
                unsigned pk = __builtin_amdgcn_cvt_pk_fp8_f32(v, v, 0u, false);
                hp[c * 16] = (unsigned char)(pk & 0xFFu);
            }
        }
    }
}

// ---------- fused gather: fp8 operand rows, packed-f32 accumulate ----------
// 16 lanes/row, dsts from perm (degree-sorted). All independent loads
// issued together; entries 0..7 of every csr row are valid. Epilogue:
// bias+relu, bf16 hi/lo split into LDS MFMA chunk layout (136-short stride).

__device__ __forceinline__ void gather16_fp8_to_lds(const unsigned char* __restrict__ ht,
                                                    const int* __restrict__ cnt,
                                                    const int* __restrict__ csr,
                                                    const float* __restrict__ dinv,
                                                    const float* __restrict__ bias,
                                                    const int* __restrict__ perm,
                                                    int n, unsigned short* __restrict__ ldsA) {
    int g = threadIdx.x >> 4;             // 0..15 : dst slot
    int l = threadIdx.x & 15;             // 16 lanes x 8 features
    int d = perm[blockIdx.x * 16 + g];    // degree-sorted dst (always valid)
    const unsigned char* hb = ht + l * 8;
    const int4* c4 = (const int4*)(csr + (size_t)d * CSR_STRIDE);
    // issue all independent loads up front
    int4 ea0 = c4[0], ea1 = c4[1];
    int4 eb0 = c4[2], eb1 = c4[3];        // values only; deref guarded by lenp
    uint2 sv = *(const uint2*)(hb + (size_t)d * 128);    // self row (pre-scaled)
    int len = cnt[d];
    uint2 p0 = *(const uint2*)(hb + (size_t)ea0.x * 128);
    uint2 p1 = *(const uint2*)(hb + (size_t)ea0.y * 128);
    uint2 p2 = *(const uint2*)(hb + (size_t)ea0.z * 128);
    uint2 p3 = *(const uint2*)(hb + (size_t)ea0.w * 128);
    uint2 p4 = *(const uint2*)(hb + (size_t)ea1.x * 128);
    uint2 p5 = *(const uint2*)(hb + (size_t)ea1.y * 128);
    uint2 p6 = *(const uint2*)(hb + (size_t)ea1.z * 128);
    uint2 p7 = *(const uint2*)(hb + (size_t)ea1.w * 128);
    floatx2 s2[4];
    #pragma unroll
    for (int j = 0; j < 4; j++) s2[j] = (floatx2){0.f, 0.f};
    fp8x8_acc(s2, sv);
    int lenp = (len + 7) & ~7;            // padded length (multiple of 8, >= 8)
    if (lenp < 8) lenp = 8;
    for (int it = 8; it < lenp; it += 8) {
        int qidx = (it >> 2) + 2;
        int i0 = qidx > 14 ? 14 : qidx;
        int i1 = qidx + 1 > 15 ? 15 : qidx + 1;
        int4 ec0 = c4[i0];                       // next csr pair (issued first)
        int4 ec1 = c4[i1];
        uint2 q0 = *(const uint2*)(hb + (size_t)eb0.x * 128);
        uint2 q1 = *(const uint2*)(hb + (size_t)eb0.y * 128);
        uint2 q2 = *(const uint2*)(hb + (size_t)eb0.z * 128);
        uint2 q3 = *(const uint2*)(hb + (size_t)eb0.w * 128);
        uint2 q4 = *(const uint2*)(hb + (size_t)eb1.x * 128);
        uint2 q5 = *(const uint2*)(hb + (size_t)eb1.y * 128);
        uint2 q6 = *(const uint2*)(hb + (size_t)eb1.z * 128);
        uint2 q7 = *(const uint2*)(hb + (size_t)eb1.w * 128);
        fp8x8_acc(s2, p0); fp8x8_acc(s2, p1); fp8x8_acc(s2, p2); fp8x8_acc(s2, p3);
        fp8x8_acc(s2, p4); fp8x8_acc(s2, p5); fp8x8_acc(s2, p6); fp8x8_acc(s2, p7);
        p0 = q0; p1 = q1; p2 = q2; p3 = q3;
        p4 = q4; p5 = q5; p6 = q6; p7 = q7;
        eb0 = ec0; eb1 = ec1;
    }
    fp8x8_acc(s2, p0); fp8x8_acc(s2, p1); fp8x8_acc(s2, p2); fp8x8_acc(s2, p3);
    fp8x8_acc(s2, p4); fp8x8_acc(s2, p5); fp8x8_acc(s2, p6); fp8x8_acc(s2, p7);
    float dd = dinv[d];
    const float4* b4 = (const float4*)bias;
    float4 ba = b4[l * 2 + 0];
    float4 bq = b4[l * 2 + 1];
    float o[8];
    o[0] = fmaf(s2[0][0], dd, ba.x);
    o[1] = fmaf(s2[0][1], dd, ba.y);
    o[2] = fmaf(s2[1][0], dd, ba.z);
    o[3] = fmaf(s2[1][1], dd, ba.w);
    o[4] = fmaf(s2[2][0], dd, bq.x);
    o[5] = fmaf(s2[2][1], dd, bq.y);
    o[6] = fmaf(s2[3][0], dd, bq.z);
    o[7] = fmaf(s2[3][1], dd, bq.w);
    short8 h8, l8;
    #pragma unroll
    for (int j = 0; j < 8; j++) {
        float v = fmaxf(o[j], 0.f);       // relu (hidden layer)
        unsigned short sh, sl;
        split2(v, sh, sl);
        h8[j] = (short)sh;
        l8[j] = (short)sl;
    }
    *(short8*)&ldsA[g * 136 + l * 8] = h8;
    *(short8*)&ldsA[2176 + g * 136 + l * 8] = l8;
}

// A-fragment read: pure ds_read_b128, split already done by the gather.
__device__ __forceinline__ void lds_afrag16(const unsigned short* __restrict__ ldsA,
                                            short8 ah[4], short8 al[4]) {
    int lane = threadIdx.x & 63;
    int m = lane & 15, kq = lane >> 4;
    #pragma unroll
    for (int s = 0; s < 4; s++) {
        int c = 4 * s + kq;               // chunk = (s*32 + kq*8)/8
        ah[s] = *(const short8*)&ldsA[m * 136 + c * 8];
        al[s] = *(const short8*)&ldsA[2176 + m * 136 + c * 8];
    }
}

// layer1 gather (fp8 operand) + combined GEMM (Wc = W2@Wout):
// writes z[perm-row][64] fp16 = (g1 @ Wc) * dinv  (cols 48..63 unused)
__global__ __launch_bounds__(256) void gather_gemm_hidden(const unsigned char* __restrict__ ht,
                                                          const int* __restrict__ cnt,
                                                          const int* __restrict__ csr,
                                                          const float* __restrict__ dinv,
                                                          const float* __restrict__ bias,
                                                          const unsigned short* __restrict__ Wf,
                                                          const int* __restrict__ perm,
                                                          f16* __restrict__ z, int n) {
    __shared__ __align__(16) unsigned short ldsA[4352];   // hi[16][136] lo[16][136]
    gather16_fp8_to_lds(ht, cnt, csr, dinv, bias, perm, n, ldsA);
    __syncthreads();
    int wave = threadIdx.x >> 6, lane = threadIdx.x & 63;
    if (wave == 3) return;                    // cols 48..63 never consumed
    short8 ah[4], al[4];
    lds_afrag16(ldsA, ah, al);
    int m = lane & 15, kq = lane >> 4;
    int c = wave;                             // 3 col-tiles (48 cols)
    floatx4 acc = (floatx4){0.f, 0.f, 0.f, 0.f};
    #pragma unroll
    for (int s = 0; s < 4; s++) {
        int fo = ((c * 4 + s) * 64 + lane) * 8;
        short8 bhi = *(const short8*)&Wf[fo];
        short8 blo = *(const short8*)&Wf[6144 + fo];
        acc = __builtin_amdgcn_mfma_f32_16x16x32_bf16(ah[s], bhi, acc, 0, 0, 0);
        acc = __builtin_amdgcn_mfma_f32_16x16x32_bf16(al[s], bhi, acc, 0, 0, 0);
        acc = __builtin_amdgcn_mfma_f32_16x16x32_bf16(ah[s], blo, acc, 0, 0, 0);
    }
    #pragma unroll
    for (int r = 0; r < 4; r++) {
        int row = perm[blockIdx.x * 16 + kq * 4 + r];
        z[(size_t)row * 64 + c * 16 + m] = (f16)(acc[r] * dinv[row]);
    }
}

// final: pure gather over 128 B z-rows (perm order) + scale + bc -> out [n][40]
// lanes 12..15 read undefined z cols 48..63; sums discarded (l<10 writes).
#define H4ACC(P) { s0 += (float)P[0]; s1 += (float)P[1]; s2 += (float)P[2]; s3 += (float)P[3]; }

__global__ __launch_bounds__(256) void gather_out(const f16* __restrict__ z,
                                                  const int* __restrict__ cnt,
                                                  const int* __restrict__ csr,
                                                  const float* __restrict__ dinv,
                                                  const float* __restrict__ bc,
                                                  const int* __restrict__ perm,
                                                  float* __restrict__ out, int n) {
    int g = threadIdx.x >> 4;             // 0..15 : dst slot
    int l = threadIdx.x & 15;             // 16 lanes x 4 features (64-halved row)
    int d = perm[blockIdx.x * 16 + g];    // degree-sorted dst (always valid)
    const f16* zb = z + l * 4;
    const int4* c4 = (const int4*)(csr + (size_t)d * CSR_STRIDE);
    // issue all independent loads up front
    int4 ea0 = c4[0], ea1 = c4[1];
    int4 eb0 = c4[2], eb1 = c4[3];
    half4 sv = *(const half4*)(zb + (size_t)d * 64);     // self row (pre-scaled)
    int len = cnt[d];
    half4 p0 = *(const half4*)(zb + (size_t)ea0.x * 64);
    half4 p1 = *(const half4*)(zb + (size_t)ea0.y * 64);
    half4 p2 = *(const half4*)(zb + (size_t)ea0.z * 64);
    half4 p3 = *(const half4*)(zb + (size_t)ea0.w * 64);
    half4 p4 = *(const half4*)(zb + (size_t)ea1.x * 64);
    half4 p5 = *(const half4*)(zb + (size_t)ea1.y * 64);
    half4 p6 = *(const half4*)(zb + (size_t)ea1.z * 64);
    half4 p7 = *(const half4*)(zb + (size_t)ea1.w * 64);
    float s0 = (float)sv[0], s1 = (float)sv[1], s2 = (float)sv[2], s3 = (float)sv[3];
    int lenp = (len + 7) & ~7;            // padded length (multiple of 8, >= 8)
    if (lenp < 8) lenp = 8;
    for (int it = 8; it < lenp; it += 8) {
        int qidx = (it >> 2) + 2;
        int i0 = qidx > 14 ? 14 : qidx;
        int i1 = qidx + 1 > 15 ? 15 : qidx + 1;
        int4 ec0 = c4[i0];                       // next csr pair (issued first)
        int4 ec1 = c4[i1];
        half4 q0 = *(const half4*)(zb + (size_t)eb0.x * 64);
        half4 q1 = *(const half4*)(zb + (size_t)eb0.y * 64);
        half4 q2 = *(const half4*)(zb + (size_t)eb0.z * 64);
        half4 q3 = *(const half4*)(zb + (size_t)eb0.w * 64);
        half4 q4 = *(const half4*)(zb + (size_t)eb1.x * 64);
        half4 q5 = *(const half4*)(zb + (size_t)eb1.y * 64);
        half4 q6 = *(const half4*)(zb + (size_t)eb1.z * 64);
        half4 q7 = *(const half4*)(zb + (size_t)eb1.w * 64);
        H4ACC(p0); H4ACC(p1); H4ACC(p2); H4ACC(p3);
        H4ACC(p4); H4ACC(p5); H4ACC(p6); H4ACC(p7);
        p0 = q0; p1 = q1; p2 = q2; p3 = q3;
        p4 = q4; p5 = q5; p6 = q6; p7 = q7;
        eb0 = ec0; eb1 = ec1;
    }
    H4ACC(p0); H4ACC(p1); H4ACC(p2); H4ACC(p3);
    H4ACC(p4); H4ACC(p5); H4ACC(p6); H4ACC(p7);
    if (l < 10) {
        float dd = dinv[d];
        float4 bb = ((const float4*)bc)[l];
        float4 o;
        o.x = fmaf(s0, dd, bb.x);
        o.y = fmaf(s1, dd, bb.y);
        o.z = fmaf(s2, dd, bb.z);
        o.w = fmaf(s3, dd, bb.w);
        *(float4*)(out + (size_t)d * 40 + l * 4) = o;
    }
}

extern "C" void kernel_launch(void* const* d_in, const int* in_sizes, int n_in,
                              void* d_out, int out_size, void* d_ws, size_t ws_size,
                              hipStream_t stream) {
    const float* x    = (const float*)d_in[0];
    const int*   ei   = (const int*)d_in[1];
    const float* W1   = (const float*)d_in[2];
    const float* b1   = (const float*)d_in[3];
    const float* W2   = (const float*)d_in[4];
    const float* b2   = (const float*)d_in[5];
    const float* Wout = (const float*)d_in[6];
    const float* bout = (const float*)d_in[7];

    int N = in_sizes[0] / 128;      // 100000
    int E = in_sizes[1] / 2;        // 1600000
    const int* srcv = ei;
    const int* dstv = ei + E;

    char* p = (char*)d_ws;
    auto alloc = [&](size_t bytes) { void* r = (void*)p; p += (bytes + 255) & ~(size_t)255; return r; };
    int*      bcur   = (int*)alloc(256 * 16 * 4);
    int*      cnt    = (int*)alloc((size_t)N * 4);
    float*    dinv   = (float*)alloc((size_t)N * 4);
    unsigned* bstore = (unsigned*)alloc((size_t)256 * BCAP2 * 4);  // 10.5 MB
    int*      csr    = (int*)alloc((size_t)N * CSR_STRIDE * 4);    // 25.6 MB
    unsigned short* wf1 = (unsigned short*)alloc(16384 * 2);
    unsigned short* wfc = (unsigned short*)alloc(12288 * 2);
    float*    Wcf    = (float*)alloc(5120 * 4);
    float*    bc     = (float*)alloc(40 * 4);
    unsigned char* ht = (unsigned char*)alloc((size_t)(N + 1) * 128);   // fp8, +1 zero row
    f16*      z      = (f16*)alloc((size_t)(N + 1) * 64 * 2);           // fp16[64]/row, +1 zero row

    int NB_B  = (N + 511) >> 9;      // 196 phase-B blocks (one per bucket)
    int*      perm   = (int*)alloc((size_t)NB_B * 512 * 4);             // degree-sorted order

    int NB_A  = (E + CH - 1) / CH;   // 391 phase-A blocks
    int NB_G  = (N + 127) / 128;
    int NB_GG = NB_B * 32;           // 6272 gather blocks (16 perm slots each)

    // fused setup (replaces wc_build + wsplit + 3 memsets)
    setup1<<<101, 256, 0, stream>>>(W2, Wout, b2, bout, W1, Wcf, bc, wf1, bcur,
                                    (unsigned*)(ht + (size_t)N * 128),
                                    (unsigned*)(z + (size_t)N * 64));
    setup2<<<24, 256, 0, stream>>>(Wcf, wfc);

    // two-phase CSR build (+ degree-sorted perm) + layer-1 GEMM
    bin_scatter<<<NB_A, 256, 0, stream>>>(srcv, dstv, bcur, bstore, E);
    bin_to_csr<<<NB_B, 1024, 0, stream>>>(bcur, bstore, csr, cnt, dinv, perm, N);
    gemm_mfma<<<NB_G, 256, 0, stream>>>(x, wf1, dinv, ht, N);

    // gather1 (+b1,relu, fp8 operand) + combined GEMM (W2@Wout) -> z fp16 [n][64]
    gather_gemm_hidden<<<NB_GG, 256, 0, stream>>>(ht, cnt, csr, dinv, b1, wfc, perm, z, N);
    // final: pure gather over 1-line z rows + bc -> out [n][40] fp32
    gather_out<<<NB_GG, 256, 0, stream>>>(z, cnt, csr, dinv, bc, perm, (float*)d_out, N);
}

// Round 15
// 216.403 us; speedup vs baseline: 1.0474x; 1.0474x over previous
//
#include <hip/hip_runtime.h>

// GCN: 2x GCNConv(128->128) + relu, then Linear(128->40).
// R23 = R21 config (217.6us session best) — resubmit after infra failure.
//  R22's degree-sorted perm REGRESSED (226.7us): perm indirection
//  re-serialized the gather front (perm -> d -> csr/cnt/self), losing R17's
//  all-independent-loads-at-cycle-0 property. Sixth structural gather attack;
//  only R17's hoisting ever helped. Per-row fixed cost is structural.
//  This build banks the best-known configuration:
//  - Fused setup (2 kernels, no memsets).
//  - 256-bucket two-phase CSR build (rows padded >=8, x8, zero-row index n).
//  - Layer-1 GEMM single-term bf16 -> fp8-e4m3 ht (128B rows, dinv-prescaled).
//  - out = A_norm (g1 @ (W2 Wout)) + (b2 Wout + bout): Wout folded, z table
//    40 feats fp16 @ stride 64 = 1 line/row (cols 48-63 never consumed).
//  - Gathers: 16 lanes/row, 8-deep pipeline, csr issued 1 iter ahead, all
//    independent loads hoisted, d = blockIdx-derived (no indirection).

typedef __attribute__((ext_vector_type(8))) short short8;
typedef __attribute__((ext_vector_type(4))) float floatx4;
typedef __attribute__((ext_vector_type(2))) float floatx2;
typedef _Float16 f16;
typedef __attribute__((ext_vector_type(4))) _Float16 half4;

#define CSR_STRIDE 64    // max in-degree ~40 for E=1.6M,N=100k
#define CH 4096          // edges per phase-A block (391 blocks)
#define BCAP2 10240      // per-bucket capacity (mean 8192, +22 sigma)

static __device__ inline unsigned short f32_to_bf16(float f) {
    unsigned u = __float_as_uint(f);
    unsigned r = (u + 0x7FFFu + ((u >> 16) & 1u)) >> 16;   // round-nearest-even
    return (unsigned short)r;
}
static __device__ inline float bf16_to_f32(unsigned short h) {
    return __uint_as_float(((unsigned)h) << 16);
}
static __device__ inline void split2(float v, unsigned short& h, unsigned short& l) {
    h = f32_to_bf16(v);
    l = f32_to_bf16(v - bf16_to_f32(h));
}
// accumulate 8 fp8(e4m3) bytes (packed in uint2) into s2[0..3] (float2 lanes)
static __device__ __forceinline__ void fp8x8_acc(floatx2* s2, uint2 v) {
    s2[0] += __builtin_amdgcn_cvt_pk_f32_fp8(v.x, false);
    s2[1] += __builtin_amdgcn_cvt_pk_f32_fp8(v.x, true);
    s2[2] += __builtin_amdgcn_cvt_pk_f32_fp8(v.y, false);
    s2[3] += __builtin_amdgcn_cvt_pk_f32_fp8(v.y, true);
}

// ---------- setup1: Wc/bc build + W1 split + bcur clear + zero rows ----------

__global__ __launch_bounds__(256) void setup1(const float* __restrict__ W2,
                                              const float* __restrict__ Wout,
                                              const float* __restrict__ b2,
                                              const float* __restrict__ bout,
                                              const float* __restrict__ W1,
                                              float* __restrict__ Wc,
                                              float* __restrict__ bc,
                                              unsigned short* __restrict__ wf1,
                                              int* __restrict__ bcur,
                                              unsigned* __restrict__ htz,
                                              unsigned* __restrict__ zz) {
    int tid = blockIdx.x * 256 + threadIdx.x;
    if (tid < 5120) {
        int i = tid / 40, j = tid - (tid / 40) * 40;
        float s = 0.f;
        for (int k = 0; k < 128; k++) s = fmaf(W2[i * 128 + k], Wout[k * 40 + j], s);
        Wc[i * 40 + j] = s;
    } else if (tid < 5160) {
        int j = tid - 5120;
        float s = bout[j];
        for (int k = 0; k < 128; k++) s = fmaf(b2[k], Wout[k * 40 + j], s);
        bc[j] = s;
    } else if (tid < 21544) {                  // W1 bf16 split (hi only)
        int e = tid - 5160;
        int k = e >> 7, nn = e & 127;
        int c = nn >> 4, s = k >> 5;
        int lane = (nn & 15) | (((k >> 3) & 3) << 4);
        int j = k & 7;
        int o = ((c * 4 + s) * 64 + lane) * 8 + j;
        wf1[o] = f32_to_bf16(W1[e]);
    } else if (tid < 25640) {                  // bcur clear (256*16 ints)
        bcur[tid - 21544] = 0;
    } else if (tid < 25672) {                  // ht zero row (128 B)
        htz[tid - 25640] = 0u;
    } else if (tid < 25704) {                  // z zero row (128 B)
        zz[tid - 25672] = 0u;
    }
}

// ---------- setup2: Wc -> frag-major bf16 hi/lo (needs Wcf from setup1) ----------

__global__ __launch_bounds__(256) void setup2(const float* __restrict__ Wcf,
                                              unsigned short* __restrict__ wfc) {
    int id = blockIdx.x * 256 + threadIdx.x;
    if (id < 6144) {                           // Wc 128x48 (cols 40..47 zero)
        int j = id & 7, lane = (id >> 3) & 63, cs = id >> 9;
        int c = cs >> 2, s = cs & 3;
        int k = s * 32 + ((lane >> 4) & 3) * 8 + j;
        int nn = c * 16 + (lane & 15);
        float v = (nn < 40) ? Wcf[k * 40 + nn] : 0.f;
        unsigned short h, l;
        split2(v, h, l);
        wfc[id] = h;
        wfc[6144 + id] = l;
    }
}

// ---------- CSR phase A: block-local binning into 256 buckets (dst>>9) ----------

__global__ __launch_bounds__(256) void bin_scatter(const int* __restrict__ src,
                                                   const int* __restrict__ dst,
                                                   int* __restrict__ bcur,
                                                   unsigned* __restrict__ bstore, int e) {
    __shared__ int hist[256];
    __shared__ int gbase[256];
    __shared__ int curs[256];
    int t = threadIdx.x;
    hist[t] = 0;
    __syncthreads();
    int tot4 = e >> 2;                       // e % 4 == 0
    int base4 = blockIdx.x * (CH / 4);
    unsigned pay[16];
    int cbv[16];
    bool vg[4];
    #pragma unroll
    for (int j = 0; j < 4; j++) {
        int i4 = base4 + t + 256 * j;
        vg[j] = (i4 < tot4);
        if (vg[j]) {
            int4 s4 = ((const int4*)src)[i4];
            int4 d4 = ((const int4*)dst)[i4];
            int dd[4] = {d4.x, d4.y, d4.z, d4.w};
            int ss[4] = {s4.x, s4.y, s4.z, s4.w};
            #pragma unroll
            for (int q = 0; q < 4; q++) {
                int cb = dd[q] >> 9;
                cbv[j * 4 + q] = cb;
                pay[j * 4 + q] = (unsigned)ss[q] | ((unsigned)(dd[q] & 511) << 17);
                atomicAdd(&hist[cb], 1);
            }
        }
    }
    __syncthreads();
    gbase[t] = atomicAdd(&bcur[t * 16], hist[t]);   // 256 returning atomics/block
    curs[t] = 0;
    __syncthreads();
    #pragma unroll
    for (int j = 0; j < 4; j++) {
        if (vg[j]) {
            #pragma unroll
            for (int q = 0; q < 4; q++) {
                int b = cbv[j * 4 + q];
                int pos = atomicAdd(&curs[b], 1);       // LDS returning atomic
                int o = gbase[b] + pos;
                if (o < BCAP2) bstore[(size_t)b * BCAP2 + o] = pay[j * 4 + q];
            }
        }
    }
}

// ---------- CSR phase B: one block per bucket, single scan; cnt+dinv fused ----------
// Pads each row to a multiple of 8 AND to at least 8 entries with index n
// (zero operand row) so gathers may read entries 0..7 before cnt resolves.

__global__ __launch_bounds__(1024) void bin_to_csr(const int* __restrict__ bcur,
                                                   const unsigned* __restrict__ bstore,
                                                   int* __restrict__ csr,
                                                   int* __restrict__ cnt,
                                                   float* __restrict__ dinv, int n) {
    __shared__ int lcur[512];
    int b = blockIdx.x;
    int t = threadIdx.x;
    if (t < 512) lcur[t] = 0;
    __syncthreads();
    int cb = bcur[b * 16];
    if (cb > BCAP2) cb = BCAP2;
    const unsigned* bs = bstore + (size_t)b * BCAP2;
    for (int i = t; i < cb; i += 1024) {
        unsigned v = bs[i];
        int dl = v >> 17;                    // 9-bit local dst
        int pos = atomicAdd(&lcur[dl], 1);
        if (pos < CSR_STRIDE) {
            int node = (b << 9) | dl;
            csr[(size_t)node * CSR_STRIDE + pos] = (int)(v & 0x1FFFFu);
        }
    }
    __syncthreads();
    if (t < 512) {
        int node = (b << 9) + t;
        if (node < n) {
            int c = min(lcur[t], CSR_STRIDE);
            cnt[node] = c;
            dinv[node] = rsqrtf((float)c + 1.0f);   // +1 self-loop
            int end = (c + 7) & ~7;
            if (end < 8) end = 8;                   // entries 0..7 always valid
            size_t base = (size_t)node * CSR_STRIDE;
            for (int k = c; k < end; k++) csr[base + k] = n;   // zero row
        }
    }
}

// ---------- layer-1 GEMM (LDS-staged, single bf16 term): ht = fp8((x@W1)*dinv) ----------

__global__ __launch_bounds__(256, 2) void gemm_mfma(const float* __restrict__ A,
                                                    const unsigned short* __restrict__ Wf,
                                                    const float* __restrict__ dinv,
                                                    unsigned char* __restrict__ ht, int M) {
    __shared__ __align__(16) unsigned short Wl[16384];   // hi only
    {
        const float4* wsrc = (const float4*)Wf;
        float4* wdst = (float4*)Wl;
        #pragma unroll
        for (int i = 0; i < 8; i++) wdst[threadIdx.x + 256 * i] = wsrc[threadIdx.x + 256 * i];
    }
    int wave = threadIdx.x >> 6, lane = threadIdx.x & 63;
    int mlo = lane & 15, kq = lane >> 4;
    int row_base = blockIdx.x * 128 + wave * 32;

    short8 a[2][4];
    #pragma unroll
    for (int rt = 0; rt < 2; rt++) {
        int row = row_base + rt * 16 + mlo;
        if (row > M - 1) row = M - 1;
        const float* pa = A + (size_t)row * 128 + kq * 8;
        #pragma unroll
        for (int s = 0; s < 4; s++) {
            float u[8];
            *(float4*)&u[0] = *(const float4*)(pa + s * 32);
            *(float4*)&u[4] = *(const float4*)(pa + s * 32 + 4);
            short8 ah;
            #pragma unroll
            for (int j = 0; j < 8; j++) ah[j] = (short)f32_to_bf16(u[j]);
            a[rt][s] = ah;
        }
    }
    floatx4 acc[2][8];
    #pragma unroll
    for (int rt = 0; rt < 2; rt++)
        #pragma unroll
        for (int c = 0; c < 8; c++) acc[rt][c] = (floatx4){0.f, 0.f, 0.f, 0.f};
    __syncthreads();

    #pragma unroll
    for (int c = 0; c < 8; c++) {
        #pragma unroll
        for (int s = 0; s < 4; s++) {
            int fo = ((c * 4 + s) * 64 + lane) * 8;
            short8 bhi = *(const short8*)&Wl[fo];
            #pragma unroll
            for (int rt = 0; rt < 2; rt++)
                acc[rt][c] = __builtin_amdgcn_mfma_f32_16x16x32_bf16(a[rt][s], bhi, acc[rt][c], 0, 0, 0);
        }
    }
    #pragma unroll
    for (int rt = 0; rt < 2; rt++) {
        int r0 = row_base + rt * 16 + kq * 4;
        #pragma unroll
        for (int r = 0; r < 4; r++) {
            int row = r0 + r;
            if (row >= M) continue;
            float dd = dinv[row];
            unsigned char* hp = ht + (size_t)row * 128 + mlo;
            #pragma unroll
            for (int c = 0; c < 8; c++) {
                float v = acc[rt][c][r] * dd;
                unsigned pk = __builtin_amdgcn_cvt_pk_fp8_f32(v, v, 0u, false);
                hp[c * 16] = (unsigned char)(pk & 0xFFu);
            }
        }
    }
}

// ---------- fused gather: fp8 operand rows, packed-f32 accumulate ----------
// 16 lanes/row. All independent loads (csr[0..3], self, cnt) issued together;
// entries 0..7 of every csr row are valid, so row loads chain off csr only.
// Epilogue: bias+relu, then bf16 hi/lo split written straight into LDS in
// MFMA chunk layout (row stride 136 shorts -> even bank tiling).

__device__ __forceinline__ void gather16_fp8_to_lds(const unsigned char* __restrict__ ht,
                                                    const int* __restrict__ cnt,
                                                    const int* __restrict__ csr,
                                                    const float* __restrict__ dinv,
                                                    const float* __restrict__ bias,
                                                    int n, unsigned short* __restrict__ ldsA) {
    int g = threadIdx.x >> 4;             // 0..15 : dst slot
    int l = threadIdx.x & 15;             // 16 lanes x 8 features
    int d = blockIdx.x * 16 + g;
    if (d >= n) return;
    const unsigned char* hb = ht + l * 8;
    const int4* c4 = (const int4*)(csr + (size_t)d * CSR_STRIDE);
    // issue all independent loads up front
    int4 ea0 = c4[0], ea1 = c4[1];
    int4 eb0 = c4[2], eb1 = c4[3];        // values only; deref guarded by lenp
    uint2 sv = *(const uint2*)(hb + (size_t)d * 128);    // self row (pre-scaled)
    int len = cnt[d];
    uint2 p0 = *(const uint2*)(hb + (size_t)ea0.x * 128);
    uint2 p1 = *(const uint2*)(hb + (size_t)ea0.y * 128);
    uint2 p2 = *(const uint2*)(hb + (size_t)ea0.z * 128);
    uint2 p3 = *(const uint2*)(hb + (size_t)ea0.w * 128);
    uint2 p4 = *(const uint2*)(hb + (size_t)ea1.x * 128);
    uint2 p5 = *(const uint2*)(hb + (size_t)ea1.y * 128);
    uint2 p6 = *(const uint2*)(hb + (size_t)ea1.z * 128);
    uint2 p7 = *(const uint2*)(hb + (size_t)ea1.w * 128);
    floatx2 s2[4];
    #pragma unroll
    for (int j = 0; j < 4; j++) s2[j] = (floatx2){0.f, 0.f};
    fp8x8_acc(s2, sv);
    int lenp = (len + 7) & ~7;            // padded length (multiple of 8, >= 8)
    if (lenp < 8) lenp = 8;
    for (int it = 8; it < lenp; it += 8) {
        int qidx = (it >> 2) + 2;
        int i0 = qidx > 14 ? 14 : qidx;
        int i1 = qidx + 1 > 15 ? 15 : qidx + 1;
        int4 ec0 = c4[i0];                       // next csr pair (issued first)
        int4 ec1 = c4[i1];
        uint2 q0 = *(const uint2*)(hb + (size_t)eb0.x * 128);
        uint2 q1 = *(const uint2*)(hb + (size_t)eb0.y * 128);
        uint2 q2 = *(const uint2*)(hb + (size_t)eb0.z * 128);
        uint2 q3 = *(const uint2*)(hb + (size_t)eb0.w * 128);
        uint2 q4 = *(const uint2*)(hb + (size_t)eb1.x * 128);
        uint2 q5 = *(const uint2*)(hb + (size_t)eb1.y * 128);
        uint2 q6 = *(const uint2*)(hb + (size_t)eb1.z * 128);
        uint2 q7 = *(const uint2*)(hb + (size_t)eb1.w * 128);
        fp8x8_acc(s2, p0); fp8x8_acc(s2, p1); fp8x8_acc(s2, p2); fp8x8_acc(s2, p3);
        fp8x8_acc(s2, p4); fp8x8_acc(s2, p5); fp8x8_acc(s2, p6); fp8x8_acc(s2, p7);
        p0 = q0; p1 = q1; p2 = q2; p3 = q3;
        p4 = q4; p5 = q5; p6 = q6; p7 = q7;
        eb0 = ec0; eb1 = ec1;
    }
    fp8x8_acc(s2, p0); fp8x8_acc(s2, p1); fp8x8_acc(s2, p2); fp8x8_acc(s2, p3);
    fp8x8_acc(s2, p4); fp8x8_acc(s2, p5); fp8x8_acc(s2, p6); fp8x8_acc(s2, p7);
    float dd = dinv[d];
    const float4* b4 = (const float4*)bias;
    float4 ba = b4[l * 2 + 0];
    float4 bq = b4[l * 2 + 1];
    float o[8];
    o[0] = fmaf(s2[0][0], dd, ba.x);
    o[1] = fmaf(s2[0][1], dd, ba.y);
    o[2] = fmaf(s2[1][0], dd, ba.z);
    o[3] = fmaf(s2[1][1], dd, ba.w);
    o[4] = fmaf(s2[2][0], dd, bq.x);
    o[5] = fmaf(s2[2][1], dd, bq.y);
    o[6] = fmaf(s2[3][0], dd, bq.z);
    o[7] = fmaf(s2[3][1], dd, bq.w);
    short8 h8, l8;
    #pragma unroll
    for (int j = 0; j < 8; j++) {
        float v = fmaxf(o[j], 0.f);       // relu (hidden layer)
        unsigned short sh, sl;
        split2(v, sh, sl);
        h8[j] = (short)sh;
        l8[j] = (short)sl;
    }
    *(short8*)&ldsA[g * 136 + l * 8] = h8;
    *(short8*)&ldsA[2176 + g * 136 + l * 8] = l8;
}

// A-fragment read: pure ds_read_b128, split already done by the gather.
__device__ __forceinline__ void lds_afrag16(const unsigned short* __restrict__ ldsA,
                                            short8 ah[4], short8 al[4]) {
    int lane = threadIdx.x & 63;
    int m = lane & 15, kq = lane >> 4;
    #pragma unroll
    for (int s = 0; s < 4; s++) {
        int c = 4 * s + kq;               // chunk = (s*32 + kq*8)/8
        ah[s] = *(const short8*)&ldsA[m * 136 + c * 8];
        al[s] = *(const short8*)&ldsA[2176 + m * 136 + c * 8];
    }
}

// layer1 gather (fp8 operand) + combined GEMM (Wc = W2@Wout):
// writes z[n][64] fp16 = (g1 @ Wc) * dinv  (cols 0..47 valid; 48..63 unused)
__global__ __launch_bounds__(256) void gather_gemm_hidden(const unsigned char* __restrict__ ht,
                                                          const int* __restrict__ cnt,
                                                          const int* __restrict__ csr,
                                                          const float* __restrict__ dinv,
                                                          const float* __restrict__ bias,
                                                          const unsigned short* __restrict__ Wf,
                                                          f16* __restrict__ z, int n) {
    __shared__ __align__(16) unsigned short ldsA[4352];   // hi[16][136] lo[16][136]
    gather16_fp8_to_lds(ht, cnt, csr, dinv, bias, n, ldsA);
    __syncthreads();
    int wave = threadIdx.x >> 6, lane = threadIdx.x & 63;
    if (wave == 3) return;                    // cols 48..63 never consumed
    short8 ah[4], al[4];
    lds_afrag16(ldsA, ah, al);
    int m = lane & 15, kq = lane >> 4;
    int c = wave;                             // 3 col-tiles (48 cols)
    floatx4 acc = (floatx4){0.f, 0.f, 0.f, 0.f};
    #pragma unroll
    for (int s = 0; s < 4; s++) {
        int fo = ((c * 4 + s) * 64 + lane) * 8;
        short8 bhi = *(const short8*)&Wf[fo];
        short8 blo = *(const short8*)&Wf[6144 + fo];
        acc = __builtin_amdgcn_mfma_f32_16x16x32_bf16(ah[s], bhi, acc, 0, 0, 0);
        acc = __builtin_amdgcn_mfma_f32_16x16x32_bf16(al[s], bhi, acc, 0, 0, 0);
        acc = __builtin_amdgcn_mfma_f32_16x16x32_bf16(ah[s], blo, acc, 0, 0, 0);
    }
    #pragma unroll
    for (int r = 0; r < 4; r++) {
        int row = blockIdx.x * 16 + kq * 4 + r;
        if (row < n) z[(size_t)row * 64 + c * 16 + m] = (f16)(acc[r] * dinv[row]);
    }
}

// final: pure gather over 128 B z-rows + scale + bc -> out [n][40] fp32
// lanes 12..15 read undefined z cols 48..63; their sums are discarded (l<10).
#define H4ACC(P) { s0 += (float)P[0]; s1 += (float)P[1]; s2 += (float)P[2]; s3 += (float)P[3]; }

__global__ __launch_bounds__(256) void gather_out(const f16* __restrict__ z,
                                                  const int* __restrict__ cnt,
                                                  const int* __restrict__ csr,
                                                  const float* __restrict__ dinv,
                                                  const float* __restrict__ bc,
                                                  float* __restrict__ out, int n) {
    int g = threadIdx.x >> 4;             // 0..15 : dst slot
    int l = threadIdx.x & 15;             // 16 lanes x 4 features (64-halved row)
    int d = blockIdx.x * 16 + g;
    if (d >= n) return;
    const f16* zb = z + l * 4;
    const int4* c4 = (const int4*)(csr + (size_t)d * CSR_STRIDE);
    // issue all independent loads up front
    int4 ea0 = c4[0], ea1 = c4[1];
    int4 eb0 = c4[2], eb1 = c4[3];
    half4 sv = *(const half4*)(zb + (size_t)d * 64);     // self row (pre-scaled)
    int len = cnt[d];
    half4 p0 = *(const half4*)(zb + (size_t)ea0.x * 64);
    half4 p1 = *(const half4*)(zb + (size_t)ea0.y * 64);
    half4 p2 = *(const half4*)(zb + (size_t)ea0.z * 64);
    half4 p3 = *(const half4*)(zb + (size_t)ea0.w * 64);
    half4 p4 = *(const half4*)(zb + (size_t)ea1.x * 64);
    half4 p5 = *(const half4*)(zb + (size_t)ea1.y * 64);
    half4 p6 = *(const half4*)(zb + (size_t)ea1.z * 64);
    half4 p7 = *(const half4*)(zb + (size_t)ea1.w * 64);
    float s0 = (float)sv[0], s1 = (float)sv[1], s2 = (float)sv[2], s3 = (float)sv[3];
    int lenp = (len + 7) & ~7;            // padded length (multiple of 8, >= 8)
    if (lenp < 8) lenp = 8;
    for (int it = 8; it < lenp; it += 8) {
        int qidx = (it >> 2) + 2;
        int i0 = qidx > 14 ? 14 : qidx;
        int i1 = qidx + 1 > 15 ? 15 : qidx + 1;
        int4 ec0 = c4[i0];                       // next csr pair (issued first)
        int4 ec1 = c4[i1];
        half4 q0 = *(const half4*)(zb + (size_t)eb0.x * 64);
        half4 q1 = *(const half4*)(zb + (size_t)eb0.y * 64);
        half4 q2 = *(const half4*)(zb + (size_t)eb0.z * 64);
        half4 q3 = *(const half4*)(zb + (size_t)eb0.w * 64);
        half4 q4 = *(const half4*)(zb + (size_t)eb1.x * 64);
        half4 q5 = *(const half4*)(zb + (size_t)eb1.y * 64);
        half4 q6 = *(const half4*)(zb + (size_t)eb1.z * 64);
        half4 q7 = *(const half4*)(zb + (size_t)eb1.w * 64);
        H4ACC(p0); H4ACC(p1); H4ACC(p2); H4ACC(p3);
        H4ACC(p4); H4ACC(p5); H4ACC(p6); H4ACC(p7);
        p0 = q0; p1 = q1; p2 = q2; p3 = q3;
        p4 = q4; p5 = q5; p6 = q6; p7 = q7;
        eb0 = ec0; eb1 = ec1;
    }
    H4ACC(p0); H4ACC(p1); H4ACC(p2); H4ACC(p3);
    H4ACC(p4); H4ACC(p5); H4ACC(p6); H4ACC(p7);
    if (l < 10) {
        float dd = dinv[d];
        float4 bb = ((const float4*)bc)[l];
        float4 o;
        o.x = fmaf(s0, dd, bb.x);
        o.y = fmaf(s1, dd, bb.y);
        o.z = fmaf(s2, dd, bb.z);
        o.w = fmaf(s3, dd, bb.w);
        *(float4*)(out + (size_t)d * 40 + l * 4) = o;
    }
}

extern "C" void kernel_launch(void* const* d_in, const int* in_sizes, int n_in,
                              void* d_out, int out_size, void* d_ws, size_t ws_size,
                              hipStream_t stream) {
    const float* x    = (const float*)d_in[0];
    const int*   ei   = (const int*)d_in[1];
    const float* W1   = (const float*)d_in[2];
    const float* b1   = (const float*)d_in[3];
    const float* W2   = (const float*)d_in[4];
    const float* b2   = (const float*)d_in[5];
    const float* Wout = (const float*)d_in[6];
    const float* bout = (const float*)d_in[7];

    int N = in_sizes[0] / 128;      // 100000
    int E = in_sizes[1] / 2;        // 1600000
    const int* srcv = ei;
    const int* dstv = ei + E;

    char* p = (char*)d_ws;
    auto alloc = [&](size_t bytes) { void* r = (void*)p; p += (bytes + 255) & ~(size_t)255; return r; };
    int*      bcur   = (int*)alloc(256 * 16 * 4);
    int*      cnt    = (int*)alloc((size_t)N * 4);
    float*    dinv   = (float*)alloc((size_t)N * 4);
    unsigned* bstore = (unsigned*)alloc((size_t)256 * BCAP2 * 4);  // 10.5 MB
    int*      csr    = (int*)alloc((size_t)N * CSR_STRIDE * 4);    // 25.6 MB
    unsigned short* wf1 = (unsigned short*)alloc(16384 * 2);
    unsigned short* wfc = (unsigned short*)alloc(12288 * 2);
    float*    Wcf    = (float*)alloc(5120 * 4);
    float*    bc     = (float*)alloc(40 * 4);
    unsigned char* ht = (unsigned char*)alloc((size_t)(N + 1) * 128);   // fp8, +1 zero row
    f16*      z      = (f16*)alloc((size_t)(N + 1) * 64 * 2);           // fp16[64]/row, +1 zero row

    int NB_A  = (E + CH - 1) / CH;   // 391 phase-A blocks
    int NB_B  = (N + 511) >> 9;      // 196 phase-B blocks (one per bucket)
    int NB_G  = (N + 127) / 128;
    int NB_GG = (N + 15) / 16;

    // fused setup (replaces wc_build + wsplit + 3 memsets)
    setup1<<<101, 256, 0, stream>>>(W2, Wout, b2, bout, W1, Wcf, bc, wf1, bcur,
                                    (unsigned*)(ht + (size_t)N * 128),
                                    (unsigned*)(z + (size_t)N * 64));
    setup2<<<24, 256, 0, stream>>>(Wcf, wfc);

    // two-phase CSR build + CSR-independent layer-1 GEMM (pre-scaled by dinv)
    bin_scatter<<<NB_A, 256, 0, stream>>>(srcv, dstv, bcur, bstore, E);
    bin_to_csr<<<NB_B, 1024, 0, stream>>>(bcur, bstore, csr, cnt, dinv, N);
    gemm_mfma<<<NB_G, 256, 0, stream>>>(x, wf1, dinv, ht, N);

    // gather1 (+b1,relu, fp8 operand) + combined GEMM (W2@Wout) -> z fp16 [n][64]
    gather_gemm_hidden<<<NB_GG, 256, 0, stream>>>(ht, cnt, csr, dinv, b1, wfc, z, N);
    // final: pure gather over 1-line z rows + bc -> out [n][40] fp32
    gather_out<<<NB_GG, 256, 0, stream>>>(z, cnt, csr, dinv, bc, (float*)d_out, N);
}